// Round 11
// baseline (143.416 us; speedup 1.0000x reference)
//
#include <hip/hip_runtime.h>

// D2Q9 MRT (Gram-Schmidt) LBM on 1024x1024, 4 iterations.
// Barrier-free streaming chain (pull form), 5 kernels:
//   k0 : AoS -> SoA transpose only     (coalesced f4 + LDS bounce)
//   k1 : S1 C1   (pull: own-f4 loads + wave shfl edge exchange, no LDS)
//   k2 : S2 C2
//   k3 : S3 C3
//   k4 : S4 C4 + AoS write (LDS transpose out)
// Pull: f_q(x,y) = src_q(x-ex_q, y-ey_q). x-shift = row base select (branch-
// free &); y-shift = aligned own-f4 + __shfl_up/down for the edge float, with
// the 2 wave-boundary lanes patched by an exec-masked scalar global load.
// k1..k3 have NO __syncthreads and NO LDS -> no vmcnt(0) barrier drain.

#define NXD 1024
#define NYD 1024
#define NCELL (NXD * NYD)
#define ROWF (NYD * 9)      // floats per AoS row
#define HALF (NYD / 2)      // cells per 128-thread block (half row)
#define HROWF (HALF * 9)    // floats per AoS half-row = 4608

// TAU=0.6, GX=0 (exact no-op), GY=-1e-4
constexpr float INV_TAU = (float)(1.0 / 0.6);
constexpr float TGY     = (float)(0.6 * -1e-4);   // TAU*GY

__device__ __forceinline__ void collide1(
    float f0, float f1, float f2, float f3, float f4,
    float f5, float f6, float f7, float f8,
    const float (&w)[7],
    float& o0, float& o1, float& o2, float& o3, float& o4,
    float& o5, float& o6, float& o7, float& o8)
{
    const float rho = f0 + f1 + f2 + f3 + f4 + f5 + f6 + f7 + f8;
    const float jx0 = f1 - f3 + f5 - f6 - f7 + f8;
    const float jy0 = f2 - f4 + f5 + f6 - f7 - f8;
    const float vx = jx0 / rho;
    const float vy = jy0 / rho;
    const float uy = vy + TGY * rho;          // ux == vx (GX=0)
    const float jx = rho * vx;
    const float jy = rho * uy;
    const float j2 = jx * jx + jy * jy;

    const float ax = f1 + f2 + f3 + f4;
    const float dg = f5 + f6 + f7 + f8;
    const float m3 = -4.f * f0 - ax + 2.f * dg;
    const float m4 =  4.f * f0 - 2.f * ax + dg;
    const float m5 = -2.f * f1 + 2.f * f3 + f5 - f6 - f7 + f8;
    const float m6 = -2.f * f2 + 2.f * f4 + f5 + f6 - f7 - f8;
    const float m7 = f1 - f2 + f3 - f4;
    const float m8 = f5 - f6 + f7 - f8;

    const float me3 = w[0] * rho + w[1] * j2;
    const float me4 = w[2] * rho - w[3] * j2;
    const float me5 = w[4] * jx;
    const float me6 = w[4] * jy;
    const float me7 = w[5] * (jx * jx - jy * jy);
    const float me8 = w[6] * (jx * jy);

    const float mp1 = jx0 - INV_TAU * (jx0 - jx);
    const float mp2 = jy0 - INV_TAU * (jy0 - jy);
    const float mp3 = m3  - INV_TAU * (m3 - me3);
    const float mp4 = m4  - INV_TAU * (m4 - me4);
    const float mp5 = m5  - INV_TAU * (m5 - me5);
    const float mp6 = m6  - INV_TAU * (m6 - me6);
    const float mp7 = m7  - INV_TAU * (m7 - me7);
    const float mp8 = m8  - INV_TAU * (m8 - me8);

    const float s0 = rho * (1.f / 9.f);
    const float s1 = mp1 * (1.f / 6.f);
    const float s2 = mp2 * (1.f / 6.f);
    const float s3 = mp3 * (1.f / 36.f);
    const float s4 = mp4 * (1.f / 36.f);
    const float s5 = mp5 * (1.f / 12.f);
    const float s6 = mp6 * (1.f / 12.f);
    const float s7 = mp7 * 0.25f;
    const float s8 = mp8 * 0.25f;

    const float h0 = s0 - s3 - 2.f * s4;
    const float g0 = s0 + 2.f * s3 + s4;

    o0 = s0 - 4.f * s3 + 4.f * s4;
    o1 = h0 + s1 - 2.f * s5 + s7;
    o2 = h0 + s2 - 2.f * s6 - s7;
    o3 = h0 - s1 + 2.f * s5 + s7;
    o4 = h0 - s2 + 2.f * s6 - s7;
    o5 = g0 + s1 + s2 + s5 + s6 + s8;
    o6 = g0 - s1 + s2 - s5 + s6 - s8;
    o7 = g0 - s1 - s2 - s5 - s6 + s8;
    o8 = g0 + s1 - s2 + s5 - s6 - s8;
}

// collide 4 cells held as 9 float4 fragments (fully unrolled, stays in regs)
__device__ __forceinline__ void collide4(const float4 (&F)[9], float4 (&O)[9],
                                         const float (&w)[7]) {
    #pragma unroll
    for (int j = 0; j < 4; ++j) {
        float f[9], o[9];
        #pragma unroll
        for (int q = 0; q < 9; ++q)
            f[q] = ((const float*)&F[q])[j];
        collide1(f[0], f[1], f[2], f[3], f[4], f[5], f[6], f[7], f[8], w,
                 o[0], o[1], o[2], o[3], o[4], o[5], o[6], o[7], o[8]);
        #pragma unroll
        for (int q = 0; q < 9; ++q)
            ((float*)&O[q])[j] = o[q];
    }
}

__device__ __forceinline__ void load_w(const float* __restrict__ wp,
                                       float (&w)[7]) {
    #pragma unroll
    for (int i = 0; i < 7; ++i) w[i] = wp[i];
}

// edge float for ey=+1 planes: value at y0-1 (prev lane's .w; patch wave head)
__device__ __forceinline__ float edge_up(const float4 own,
                                         const float* __restrict__ rowp,
                                         int y0, int t) {
    float e = __shfl_up(own.w, 1, 64);
    if ((t & 63) == 0) e = rowp[(y0 - 1) & (NYD - 1)];
    return e;
}
// edge float for ey=-1 planes: value at y0+4 (next lane's .x; patch wave tail)
__device__ __forceinline__ float edge_dn(const float4 own,
                                         const float* __restrict__ rowp,
                                         int y0, int t) {
    float e = __shfl_down(own.x, 1, 64);
    if ((t & 63) == 63) e = rowp[(y0 + 4) & (NYD - 1)];
    return e;
}

// pull-stream the 9 fragments for cells (x, y0..y0+3) from SoA src
__device__ __forceinline__ void pull9(const float* __restrict__ src,
                                      int x, int y0, int t, float4 (&F)[9]) {
    const int xm = (x - 1) & (NXD - 1), xp = (x + 1) & (NXD - 1);
    const float* p0 = src + 0 * NCELL + x  * NYD;
    const float* p1 = src + 1 * NCELL + xm * NYD;
    const float* p2 = src + 2 * NCELL + x  * NYD;
    const float* p3 = src + 3 * NCELL + xp * NYD;
    const float* p4 = src + 4 * NCELL + x  * NYD;
    const float* p5 = src + 5 * NCELL + xm * NYD;
    const float* p6 = src + 6 * NCELL + xp * NYD;
    const float* p7 = src + 7 * NCELL + xp * NYD;
    const float* p8 = src + 8 * NCELL + xm * NYD;

    F[0] = *(const float4*)(p0 + y0);          // ey==0: own f4
    F[1] = *(const float4*)(p1 + y0);
    F[3] = *(const float4*)(p3 + y0);
    const float4 o2 = *(const float4*)(p2 + y0);
    const float4 o5 = *(const float4*)(p5 + y0);
    const float4 o6 = *(const float4*)(p6 + y0);
    const float4 o4 = *(const float4*)(p4 + y0);
    const float4 o7 = *(const float4*)(p7 + y0);
    const float4 o8 = *(const float4*)(p8 + y0);

    const float e2 = edge_up(o2, p2, y0, t);
    const float e5 = edge_up(o5, p5, y0, t);
    const float e6 = edge_up(o6, p6, y0, t);
    const float e4 = edge_dn(o4, p4, y0, t);
    const float e7 = edge_dn(o7, p7, y0, t);
    const float e8 = edge_dn(o8, p8, y0, t);

    // ey=+1 -> need y0-1..y0+2 ; ey=-1 -> need y0+1..y0+4
    F[2] = make_float4(e2, o2.x, o2.y, o2.z);
    F[5] = make_float4(e5, o5.x, o5.y, o5.z);
    F[6] = make_float4(e6, o6.x, o6.y, o6.z);
    F[4] = make_float4(o4.y, o4.z, o4.w, e4);
    F[7] = make_float4(o7.y, o7.z, o7.w, e7);
    F[8] = make_float4(o8.y, o8.z, o8.w, e8);
}

// ---- k0: AoS -> SoA transpose (no stream, no collide) ----
__global__ __launch_bounds__(128) void k0_t(const float* __restrict__ src,
                                            float* __restrict__ dst) {
    __shared__ float4 T[HROWF / 4];   // 1152 f4 = 18432 B (half AoS row)
    const int b = blockIdx.x, t = threadIdx.x;
    const int x = b >> 1, h = b & 1;

    const float4* s = (const float4*)(src + (size_t)x * ROWF + h * HROWF);
    #pragma unroll
    for (int i = 0; i < 9; ++i)
        T[t + 128 * i] = s[t + 128 * i];    // coalesced global, linear LDS
    __syncthreads();

    float4 A[9];                            // thread's 4 AoS cells (36 floats)
    #pragma unroll
    for (int k = 0; k < 9; ++k) A[k] = T[t * 9 + k];
    const float* a = (const float*)A;       // compile-time indices only

    const int c = x * NYD + h * HALF + 4 * t;
    #pragma unroll
    for (int q = 0; q < 9; ++q)
        *(float4*)(dst + q * NCELL + c) =
            make_float4(a[q], a[9 + q], a[18 + q], a[27 + q]);
}

// ---- k1..k3: Si Ci (pull), SoA -> SoA. No LDS, no barrier. ----
__global__ __launch_bounds__(128) void k_sc(const float* __restrict__ src,
                                            float* __restrict__ dst,
                                            const float* __restrict__ wp) {
    const int b = blockIdx.x, t = threadIdx.x;
    const int x  = b >> 1;
    const int y0 = (b & 1) * HALF + 4 * t;

    float4 F[9];
    pull9(src, x, y0, t, F);

    float w[7];
    load_w(wp, w);

    float4 O[9];
    collide4(F, O, w);

    const int c = x * NYD + y0;
    #pragma unroll
    for (int q = 0; q < 9; ++q)
        *(float4*)(dst + q * NCELL + c) = O[q];
}

// ---- k4: S4 C4 (pull) + AoS write via LDS transpose ----
__global__ __launch_bounds__(128) void k4_aos(const float* __restrict__ src,
                                              float* __restrict__ dst,
                                              const float* __restrict__ wp) {
    __shared__ float4 T[HROWF / 4];   // 18432 B
    const int b = blockIdx.x, t = threadIdx.x;
    const int x  = b >> 1;
    const int y0 = (b & 1) * HALF + 4 * t;

    float4 F[9];
    pull9(src, x, y0, t, F);

    float w[7];
    load_w(wp, w);

    float4 O[9];
    collide4(F, O, w);

    // thread's 4 cells in AoS order = 36 contiguous floats (flat f = j*9+q)
    float* tt = (float*)&T[t * 9];
    #pragma unroll
    for (int f = 0; f < 36; ++f)
        tt[f] = ((const float*)&O[f % 9])[f / 9];
    __syncthreads();

    float4* dv = (float4*)(dst + (size_t)x * ROWF + (b & 1) * HROWF);
    #pragma unroll
    for (int i = 0; i < 9; ++i)
        dv[t + 128 * i] = T[t + 128 * i];   // coalesced global out
}

// ---- fallback: plain AoS->AoS fused stream+collide (scalar gather) ----
__global__ __launch_bounds__(256) void lbm_step_aos(const float* __restrict__ src,
                                                    float* __restrict__ dst,
                                                    const float* __restrict__ wp) {
    const int cell = blockIdx.x * 256 + threadIdx.x;
    const int x = cell >> 10;
    const int y = cell & (NYD - 1);
    const int xm = (x + NXD - 1) & (NXD - 1);
    const int xp = (x + 1) & (NXD - 1);
    const int ym = (y + NYD - 1) & (NYD - 1);
    const int yp = (y + 1) & (NYD - 1);

    const float f0 = src[(x  * NYD + y ) * 9 + 0];
    const float f1 = src[(xm * NYD + y ) * 9 + 1];
    const float f2 = src[(x  * NYD + ym) * 9 + 2];
    const float f3 = src[(xp * NYD + y ) * 9 + 3];
    const float f4 = src[(x  * NYD + yp) * 9 + 4];
    const float f5 = src[(xm * NYD + ym) * 9 + 5];
    const float f6 = src[(xp * NYD + ym) * 9 + 6];
    const float f7 = src[(xp * NYD + yp) * 9 + 7];
    const float f8 = src[(xm * NYD + yp) * 9 + 8];

    float w[7];
    load_w(wp, w);
    float o0,o1,o2,o3,o4,o5,o6,o7,o8;
    collide1(f0,f1,f2,f3,f4,f5,f6,f7,f8, w,
             o0,o1,o2,o3,o4,o5,o6,o7,o8);

    float* o = dst + (size_t)(x * NYD + y) * 9;
    o[0]=o0; o[1]=o1; o[2]=o2; o[3]=o3; o[4]=o4; o[5]=o5; o[6]=o6; o[7]=o7; o[8]=o8;
}

extern "C" void kernel_launch(void* const* d_in, const int* in_sizes, int n_in,
                              void* d_out, int out_size, void* d_ws, size_t ws_size,
                              hipStream_t stream) {
    const float* f_in = (const float*)d_in[0];
    const float* w    = (const float*)d_in[1];
    float* out = (float*)d_out;
    float* A   = (float*)d_ws;
    const size_t bufBytes = (size_t)NCELL * 9 * sizeof(float);

    dim3 grid(NXD * 2), block(128);

    if (ws_size >= 2 * bufBytes) {
        float* B = A + (size_t)NCELL * 9;
        k0_t  <<<grid, block, 0, stream>>>(f_in, A);      // AoS -> SoA
        k_sc  <<<grid, block, 0, stream>>>(A, B, w);      // S1 C1
        k_sc  <<<grid, block, 0, stream>>>(B, A, w);      // S2 C2
        k_sc  <<<grid, block, 0, stream>>>(A, B, w);      // S3 C3
        k4_aos<<<grid, block, 0, stream>>>(B, out, w);    // S4 C4 -> AoS
    } else {
        // fallback: AoS ping-pong via d_out and mutable d_in (harness restores)
        float* fin_mut = (float*)d_in[0];
        lbm_step_aos<<<4096, 256, 0, stream>>>(f_in, out, w);
        lbm_step_aos<<<4096, 256, 0, stream>>>(out, fin_mut, w);
        lbm_step_aos<<<4096, 256, 0, stream>>>(fin_mut, out, w);
        lbm_step_aos<<<4096, 256, 0, stream>>>(out, fin_mut, w);
        hipMemcpyAsync(d_out, fin_mut, bufBytes, hipMemcpyDeviceToDevice, stream);
    }
}